// Round 1
// baseline (258.184 us; speedup 1.0000x reference)
//
#include <hip/hip_runtime.h>
#include <math.h>

#define SPIN 365
#define TRAIN 1000000
#define WARM 512
#define NPART 256   // partial-reduction blocks

// ---------------- obsstd reduction (double precision, deterministic) ----------------

__global__ void partial_std_kernel(const float* __restrict__ y, double* __restrict__ part) {
    int tid = blockIdx.x * blockDim.x + threadIdx.x;
    int stride = gridDim.x * blockDim.x;
    double s = 0.0, s2 = 0.0;
    for (int i = SPIN + tid; i < TRAIN; i += stride) {
        double v = (double)y[i];
        s += v;
        s2 += v * v;
    }
    for (int off = 32; off > 0; off >>= 1) {
        s  += __shfl_down(s,  off, 64);
        s2 += __shfl_down(s2, off, 64);
    }
    __shared__ double ls[4], ls2[4];
    int lane = threadIdx.x & 63, w = threadIdx.x >> 6;
    if (lane == 0) { ls[w] = s; ls2[w] = s2; }
    __syncthreads();
    if (threadIdx.x == 0) {
        double ts = 0.0, ts2 = 0.0;
        int nw = blockDim.x >> 6;
        for (int i = 0; i < nw; ++i) { ts += ls[i]; ts2 += ls2[i]; }
        part[2 * blockIdx.x]     = ts;
        part[2 * blockIdx.x + 1] = ts2;
    }
}

__global__ void final_std_kernel(const double* __restrict__ part, float* __restrict__ outstd) {
    double s = 0.0, s2 = 0.0;
    for (int i = threadIdx.x; i < NPART; i += blockDim.x) {
        s  += part[2 * i];
        s2 += part[2 * i + 1];
    }
    for (int off = 32; off > 0; off >>= 1) {
        s  += __shfl_down(s,  off, 64);
        s2 += __shfl_down(s2, off, 64);
    }
    __shared__ double ls[4], ls2[4];
    int lane = threadIdx.x & 63, w = threadIdx.x >> 6;
    if (lane == 0) { ls[w] = s; ls2[w] = s2; }
    __syncthreads();
    if (threadIdx.x == 0) {
        double ts = 0.0, ts2 = 0.0;
        int nw = blockDim.x >> 6;
        for (int i = 0; i < nw; ++i) { ts += ls[i]; ts2 += ls2[i]; }
        double n = (double)(TRAIN - SPIN);
        double var = (ts2 - ts * ts / n) / (n - 1.0);
        outstd[0] = (float)sqrt(var);
    }
}

// ---------------- main chunk-parallel scan ----------------

struct Par { float oo1, ol1, kz1, kz0; };

__device__ __forceinline__ void do_step(float& c, float u1, float u2, const Par p,
                                        float& oo, float& olc, float& f) {
    float z  = fmaf(c, p.kz1, p.kz0);               // b0 + (c - mo)*wb1/so
    float e  = __expf(-z);
    float sg = __builtin_amdgcn_rcpf(1.0f + e);     // sigmoid(z)
    oo = p.oo1 * sg;
    float rc = __builtin_amdgcn_rcpf(c);
    float q  = u2 * rc;
    float olc_pos = fminf(p.ol1, q);                // ol1 - relu(ol1 - u2/c)
    olc = (c > 0.0f) ? olc_pos : p.ol1;
    f = 1.0f - oo - olc;
    c = fmaf(f, c, u1);
}

__global__ void scan_kernel(const float* __restrict__ x,
                            const int*  __restrict__ time_lag_p,
                            const float* __restrict__ cm, const float* __restrict__ cs,
                            const float* __restrict__ wro, const float* __restrict__ wrl,
                            const float* __restrict__ wrf, const float* __restrict__ b0p,
                            const float* __restrict__ wb1p,
                            const float* __restrict__ obsstd_p,
                            float* __restrict__ out, int Btot) {
    const long long Bl = (long long)Btot;
    const int tl = time_lag_p[0];
    const int P  = gridDim.x * blockDim.x;
    const int tid = blockIdx.x * blockDim.x + threadIdx.x;

    // rows b < time_lag: all outputs zero
    for (int b = tid; b < tl; b += P) {
        for (int s = 0; s < 10; ++s) out[(long long)s * Bl + b] = 0.0f;
        out[10 * Bl + 2 * (long long)b]     = 0.0f;
        out[10 * Bl + 2 * (long long)b + 1] = 0.0f;
        out[12 * Bl + b] = 0.0f;
    }

    const long long N = Bl - tl;
    if (N <= 0) return;

    long long L = (N + P - 1) / P;
    L = (L + 3) & ~3LL;
    const long long j0 = (long long)tid * L;
    if (j0 >= N) return;
    const long long len = (N - j0 < L) ? (N - j0) : L;

    // uniform scalars
    const float wo = wro[0], wl = wrl[0], wf = wrf[0];
    const float b0 = b0p[0], wb1 = wb1p[0], mo = cm[0], so = cs[0];
    const float eo = __expf(wo), el = __expf(wl), ef = __expf(wf);
    const float denom = eo + el + ef;
    Par par;
    par.oo1 = eo / denom;
    par.ol1 = el / denom;
    par.kz1 = wb1 / so;
    par.kz0 = b0 - mo * par.kz1;
    const float ol1  = par.ol1;
    const float ostd = obsstd_p[0];

    const long long r0 = tl + j0;                 // first output row of this chunk
    long long wstart = r0 - WARM;
    if (wstart < tl) wstart = tl;
    float c = 0.0f;                               // exact if wstart==tl, else warm-up guess

    // ---- warm-up (no outputs), grouped-4 with prefetch ----
    {
        const long long nwarm = r0 - wstart;
        const float* xw = x + 2 * wstart;
        long long i = 0;
        float2 buf[4];
        if (i + 4 <= nwarm) {
            #pragma unroll
            for (int j = 0; j < 4; ++j) buf[j] = *(const float2*)(xw + 2 * (i + j));
        }
        while (i + 4 <= nwarm) {
            long long inext = i + 4;
            float2 nbuf[4];
            if (inext + 4 <= nwarm) {
                #pragma unroll
                for (int j = 0; j < 4; ++j) nbuf[j] = *(const float2*)(xw + 2 * (inext + j));
            } else {
                #pragma unroll
                for (int j = 0; j < 4; ++j) nbuf[j] = buf[j];
            }
            #pragma unroll
            for (int j = 0; j < 4; ++j) {
                float oo, olc, f;
                do_step(c, buf[j].x, buf[j].y, par, oo, olc, f);
            }
            #pragma unroll
            for (int j = 0; j < 4; ++j) buf[j] = nbuf[j];
            i = inext;
        }
        for (; i < nwarm; ++i) {
            float2 u = *(const float2*)(xw + 2 * i);
            float oo, olc, f;
            do_step(c, u.x, u.y, par, oo, olc, f);
        }
    }

    // ---- main chunk: compute + store all 13 output streams ----
    long long i = 0;

    // scalar head until row 4-aligned (no-op when time_lag % 4 == 0)
    while (i < len && (((r0 + i) & 3LL) != 0LL)) {
        float2 u = *(const float2*)(x + 2 * (r0 + i));
        float cpre = c, oo, olc, f;
        do_step(c, u.x, u.y, par, oo, olc, f);
        long long t = r0 + i;
        out[t]           = oo * cpre;
        out[Bl + t]      = cpre;
        out[2 * Bl + t]  = ol1 * cpre;
        out[3 * Bl + t]  = olc * cpre;
        out[4 * Bl + t]  = 0.0f;
        out[5 * Bl + t]  = 0.0f;
        out[6 * Bl + t]  = oo;
        out[7 * Bl + t]  = ol1;
        out[8 * Bl + t]  = olc;
        out[9 * Bl + t]  = f;
        out[10 * Bl + 2 * t]     = oo * cpre;
        out[10 * Bl + 2 * t + 1] = ostd;
        out[12 * Bl + t] = ostd;
        ++i;
    }

    // grouped-4 with prefetch, float4 stores (aligned: r0+i multiple of 4)
    {
        float2 buf[4];
        if (i + 4 <= len) {
            #pragma unroll
            for (int j = 0; j < 4; ++j) buf[j] = *(const float2*)(x + 2 * (r0 + i + j));
        }
        const float4 z4   = make_float4(0.0f, 0.0f, 0.0f, 0.0f);
        const float4 ol4  = make_float4(ol1, ol1, ol1, ol1);
        const float4 os4  = make_float4(ostd, ostd, ostd, ostd);
        while (i + 4 <= len) {
            long long inext = i + 4;
            float2 nbuf[4];
            if (inext + 4 <= len) {
                #pragma unroll
                for (int j = 0; j < 4; ++j) nbuf[j] = *(const float2*)(x + 2 * (r0 + inext + j));
            } else {
                #pragma unroll
                for (int j = 0; j < 4; ++j) nbuf[j] = buf[j];
            }
            float h[4], cc[4], lo[4], lc[4], go[4], gc[4], gf[4];
            #pragma unroll
            for (int j = 0; j < 4; ++j) {
                float cpre = c, oo, olc, f;
                do_step(c, buf[j].x, buf[j].y, par, oo, olc, f);
                h[j]  = oo * cpre;
                cc[j] = cpre;
                lo[j] = ol1 * cpre;
                lc[j] = olc * cpre;
                go[j] = oo;
                gc[j] = olc;
                gf[j] = f;
            }
            long long t = r0 + i;
            *(float4*)(out + t)          = make_float4(h[0], h[1], h[2], h[3]);
            *(float4*)(out + Bl + t)     = make_float4(cc[0], cc[1], cc[2], cc[3]);
            *(float4*)(out + 2 * Bl + t) = make_float4(lo[0], lo[1], lo[2], lo[3]);
            *(float4*)(out + 3 * Bl + t) = make_float4(lc[0], lc[1], lc[2], lc[3]);
            *(float4*)(out + 4 * Bl + t) = z4;
            *(float4*)(out + 5 * Bl + t) = z4;
            *(float4*)(out + 6 * Bl + t) = make_float4(go[0], go[1], go[2], go[3]);
            *(float4*)(out + 7 * Bl + t) = ol4;
            *(float4*)(out + 8 * Bl + t) = make_float4(gc[0], gc[1], gc[2], gc[3]);
            *(float4*)(out + 9 * Bl + t) = make_float4(gf[0], gf[1], gf[2], gf[3]);
            *(float4*)(out + 10 * Bl + 2 * t)     = make_float4(h[0], ostd, h[1], ostd);
            *(float4*)(out + 10 * Bl + 2 * t + 4) = make_float4(h[2], ostd, h[3], ostd);
            *(float4*)(out + 12 * Bl + t) = os4;
            #pragma unroll
            for (int j = 0; j < 4; ++j) buf[j] = nbuf[j];
            i = inext;
        }
    }

    // scalar tail
    while (i < len) {
        float2 u = *(const float2*)(x + 2 * (r0 + i));
        float cpre = c, oo, olc, f;
        do_step(c, u.x, u.y, par, oo, olc, f);
        long long t = r0 + i;
        out[t]           = oo * cpre;
        out[Bl + t]      = cpre;
        out[2 * Bl + t]  = ol1 * cpre;
        out[3 * Bl + t]  = olc * cpre;
        out[4 * Bl + t]  = 0.0f;
        out[5 * Bl + t]  = 0.0f;
        out[6 * Bl + t]  = oo;
        out[7 * Bl + t]  = ol1;
        out[8 * Bl + t]  = olc;
        out[9 * Bl + t]  = f;
        out[10 * Bl + 2 * t]     = oo * cpre;
        out[10 * Bl + 2 * t + 1] = ostd;
        out[12 * Bl + t] = ostd;
        ++i;
    }
}

// ---------------- host launch ----------------

extern "C" void kernel_launch(void* const* d_in, const int* in_sizes, int n_in,
                              void* d_out, int out_size, void* d_ws, size_t ws_size,
                              hipStream_t stream) {
    const float* x        = (const float*)d_in[0];
    // d_in[1] = epoch (unused)
    const int*   time_lag = (const int*)d_in[2];
    const float* y_obs    = (const float*)d_in[3];
    const float* c_mean   = (const float*)d_in[4];
    const float* c_std    = (const float*)d_in[5];
    const float* w_yom    = (const float*)d_in[6];
    const float* w_ylm    = (const float*)d_in[7];
    const float* w_yfm    = (const float*)d_in[8];
    const float* b0       = (const float*)d_in[9];
    const float* wb1      = (const float*)d_in[10];
    float* out = (float*)d_out;

    const int B = in_sizes[0] / 2;   // SEQ=1, IN=2

    double* part   = (double*)d_ws;
    float*  stdp   = (float*)((char*)d_ws + NPART * 2 * sizeof(double));

    partial_std_kernel<<<NPART, 256, 0, stream>>>(y_obs, part);
    final_std_kernel<<<1, 256, 0, stream>>>(part, stdp);

    // ~64 steps per thread, 64-thread blocks so all 256 CUs get work
    const int threads_target = (B + 63) / 64;           // = 31250 for B = 2e6
    const int blocks = (threads_target + 63) / 64;      // = 489
    scan_kernel<<<blocks, 64, 0, stream>>>(x, time_lag, c_mean, c_std,
                                           w_yom, w_ylm, w_yfm, b0, wb1,
                                           stdp, out, B);
}

// Round 2
// 217.235 us; speedup vs baseline: 1.1885x; 1.1885x over previous
//
#include <hip/hip_runtime.h>
#include <math.h>

#define SPIN 365
#define TRAIN 1000000
#define WARM 256
#define L 16              // output rows per thread
#define BLK 256           // threads per block
#define RPB (L * BLK)     // rows per block = 4096
#define NPART 256

// ---------------- obsstd reduction (double precision, deterministic) ----------------

__global__ void partial_std_kernel(const float* __restrict__ y, double* __restrict__ part) {
    int tid = blockIdx.x * blockDim.x + threadIdx.x;
    int stride = gridDim.x * blockDim.x;
    double s = 0.0, s2 = 0.0;
    for (int i = SPIN + tid; i < TRAIN; i += stride) {
        double v = (double)y[i];
        s += v;
        s2 += v * v;
    }
    for (int off = 32; off > 0; off >>= 1) {
        s  += __shfl_down(s,  off, 64);
        s2 += __shfl_down(s2, off, 64);
    }
    __shared__ double ls[4], ls2[4];
    int lane = threadIdx.x & 63, w = threadIdx.x >> 6;
    if (lane == 0) { ls[w] = s; ls2[w] = s2; }
    __syncthreads();
    if (threadIdx.x == 0) {
        double ts = 0.0, ts2 = 0.0;
        int nw = blockDim.x >> 6;
        for (int i = 0; i < nw; ++i) { ts += ls[i]; ts2 += ls2[i]; }
        part[2 * blockIdx.x]     = ts;
        part[2 * blockIdx.x + 1] = ts2;
    }
}

__global__ void final_std_kernel(const double* __restrict__ part, float* __restrict__ outstd) {
    double s = 0.0, s2 = 0.0;
    for (int i = threadIdx.x; i < NPART; i += blockDim.x) {
        s  += part[2 * i];
        s2 += part[2 * i + 1];
    }
    for (int off = 32; off > 0; off >>= 1) {
        s  += __shfl_down(s,  off, 64);
        s2 += __shfl_down(s2, off, 64);
    }
    __shared__ double ls[4], ls2[4];
    int lane = threadIdx.x & 63, w = threadIdx.x >> 6;
    if (lane == 0) { ls[w] = s; ls2[w] = s2; }
    __syncthreads();
    if (threadIdx.x == 0) {
        double ts = 0.0, ts2 = 0.0;
        int nw = blockDim.x >> 6;
        for (int i = 0; i < nw; ++i) { ts += ls[i]; ts2 += ls2[i]; }
        double n = (double)(TRAIN - SPIN);
        double var = (ts2 - ts * ts / n) / (n - 1.0);
        outstd[0] = (float)sqrt(var);
    }
}

// ---------------- main chunk-parallel scan ----------------

struct Par { float oo1, ol1, kz1, kz0; };

__device__ __forceinline__ void gates(float c, float u2, const Par p,
                                      float& oo, float& olc, float& f) {
    float z  = fmaf(c, p.kz1, p.kz0);               // b0 + (c - mo)*wb1/so
    float e  = __expf(-z);
    float sg = __builtin_amdgcn_rcpf(1.0f + e);     // sigmoid(z)
    oo = p.oo1 * sg;
    float rc = __builtin_amdgcn_rcpf(c);
    float q  = u2 * rc;
    float olc_pos = fminf(p.ol1, q);                // ol1 - relu(ol1 - u2/c)
    olc = (c > 0.0f) ? olc_pos : p.ol1;
    f = 1.0f - oo - olc;
}

__global__ __launch_bounds__(BLK, 2)
void scan_kernel(const float* __restrict__ x,
                 const int*  __restrict__ time_lag_p,
                 const float* __restrict__ cm, const float* __restrict__ cs,
                 const float* __restrict__ wro, const float* __restrict__ wrl,
                 const float* __restrict__ wrf, const float* __restrict__ b0p,
                 const float* __restrict__ wb1p,
                 const float* __restrict__ obsstd_p,
                 float* __restrict__ out, int Btot) {
    __shared__ float s_cpre[BLK * (L + 1)];         // pre-update state c per row (padded)

    const long long Bl = (long long)Btot;
    const int tl  = time_lag_p[0];
    const int tid = threadIdx.x;

    // rows b < time_lag: all outputs zero (grid-stride; no-op when tl == 0)
    {
        long long gstride = (long long)gridDim.x * BLK;
        for (long long b = (long long)blockIdx.x * BLK + tid; b < tl; b += gstride) {
            for (int s = 0; s < 10; ++s) out[(long long)s * Bl + b] = 0.0f;
            out[10 * Bl + 2 * b]     = 0.0f;
            out[10 * Bl + 2 * b + 1] = 0.0f;
            out[12 * Bl + b] = 0.0f;
        }
    }

    // uniform scalars
    const float wo = wro[0], wl = wrl[0], wf = wrf[0];
    const float b0 = b0p[0], wb1 = wb1p[0], mo = cm[0], so = cs[0];
    const float eo = __expf(wo), el = __expf(wl), ef = __expf(wf);
    const float denom = eo + el + ef;
    Par par;
    par.oo1 = eo / denom;
    par.ol1 = el / denom;
    par.kz1 = wb1 / so;
    par.kz0 = b0 - mo * par.kz1;
    const float ol1  = par.ol1;
    const float ostd = obsstd_p[0];

    const long long row0 = (long long)tl + (long long)blockIdx.x * RPB;  // block's first row

    // ---------------- Phase A: recurrence, c_pre -> LDS ----------------
    {
        const long long r0 = row0 + (long long)tid * L;
        long long len = Bl - r0;
        if (len < 0) len = 0;
        if (len > L) len = L;
        if (len > 0) {
            long long wstart = r0 - WARM;
            if (wstart < tl) wstart = tl;
            const int nwarm = (int)(r0 - wstart);
            const int nstep = nwarm + (int)len;
            const int ngroups = (nstep + 7) >> 3;

            float2 ring[4][8];
            const long long lastrow = Bl - 1;
            // preload 4 groups (rows clamped; clamped loads are never consumed)
            #pragma unroll
            for (int d = 0; d < 4; ++d) {
                #pragma unroll
                for (int q = 0; q < 8; ++q) {
                    long long row = wstart + (long long)d * 8 + q;
                    row = row < lastrow ? row : lastrow;
                    ring[d][q] = *(const float2*)(x + 2 * row);
                }
            }

            float c = 0.0f;                          // exact if wstart==tl, else warm guess
            int s = 0;
            float* myld = s_cpre + tid * (L + 1);
            for (int g = 0; g < ngroups; g += 4) {
                #pragma unroll
                for (int gg = 0; gg < 4; ++gg) {
                    float2 cur[8];
                    #pragma unroll
                    for (int q = 0; q < 8; ++q) cur[q] = ring[gg][q];
                    // prefetch group g+gg+4 into this slot (clamped, always safe)
                    {
                        long long base = wstart + (long long)(g + gg + 4) * 8;
                        #pragma unroll
                        for (int q = 0; q < 8; ++q) {
                            long long row = base + q;
                            row = row < lastrow ? row : lastrow;
                            ring[gg][q] = *(const float2*)(x + 2 * row);
                        }
                    }
                    #pragma unroll
                    for (int q = 0; q < 8; ++q) {
                        if (s < nstep) {
                            float oo, olc, f;
                            gates(c, cur[q].y, par, oo, olc, f);
                            int jm = s - nwarm;
                            if (jm >= 0) myld[jm] = c;   // pre-update state
                            c = fmaf(f, c, cur[q].x);
                        }
                        ++s;
                    }
                }
            }
        }
    }

    __syncthreads();

    // ---------------- Phase B: re-derive gates, coalesced stores ----------------
    const bool aligned = ((tl & 3) == 0);
    const float4 z4  = make_float4(0.0f, 0.0f, 0.0f, 0.0f);
    const float4 ol4 = make_float4(ol1, ol1, ol1, ol1);
    const float4 os4 = make_float4(ostd, ostd, ostd, ostd);

    #pragma unroll
    for (int p = 0; p < L / 4; ++p) {
        const int rl = p * (BLK * 4) + tid * 4;      // local row (multiple of 4)
        const long long r = row0 + rl;
        if (r >= Bl) continue;

        // c_pre for 4 consecutive rows (same owner thread, contiguous in LDS)
        float cp[4];
        #pragma unroll
        for (int e = 0; e < 4; ++e) {
            int rle = rl + e;
            cp[e] = s_cpre[(rle / L) * (L + 1) + (rle % L)];
        }

        if (aligned && (r + 3 < Bl)) {
            // coalesced x reread (L2-hot)
            float4 xa = *(const float4*)(x + 2 * r);
            float4 xb = *(const float4*)(x + 2 * r + 4);
            float u2v[4] = {xa.y, xa.w, xb.y, xb.w};

            float h[4], lo[4], lc[4], go[4], gc[4], gf[4];
            #pragma unroll
            for (int e = 0; e < 4; ++e) {
                float oo, olc, f;
                gates(cp[e], u2v[e], par, oo, olc, f);
                h[e]  = oo * cp[e];
                lo[e] = ol1 * cp[e];
                lc[e] = olc * cp[e];
                go[e] = oo;
                gc[e] = olc;
                gf[e] = f;
            }
            *(float4*)(out + r)          = make_float4(h[0], h[1], h[2], h[3]);
            *(float4*)(out + Bl + r)     = make_float4(cp[0], cp[1], cp[2], cp[3]);
            *(float4*)(out + 2 * Bl + r) = make_float4(lo[0], lo[1], lo[2], lo[3]);
            *(float4*)(out + 3 * Bl + r) = make_float4(lc[0], lc[1], lc[2], lc[3]);
            *(float4*)(out + 4 * Bl + r) = z4;
            *(float4*)(out + 5 * Bl + r) = z4;
            *(float4*)(out + 6 * Bl + r) = make_float4(go[0], go[1], go[2], go[3]);
            *(float4*)(out + 7 * Bl + r) = ol4;
            *(float4*)(out + 8 * Bl + r) = make_float4(gc[0], gc[1], gc[2], gc[3]);
            *(float4*)(out + 9 * Bl + r) = make_float4(gf[0], gf[1], gf[2], gf[3]);
            *(float4*)(out + 10 * Bl + 2 * r)     = make_float4(h[0], ostd, h[1], ostd);
            *(float4*)(out + 10 * Bl + 2 * r + 4) = make_float4(h[2], ostd, h[3], ostd);
            *(float4*)(out + 12 * Bl + r) = os4;
        } else {
            #pragma unroll
            for (int e = 0; e < 4; ++e) {
                long long t = r + e;
                if (t >= Bl) break;
                float2 u = *(const float2*)(x + 2 * t);
                float oo, olc, f;
                gates(cp[e], u.y, par, oo, olc, f);
                float h = oo * cp[e];
                out[t]           = h;
                out[Bl + t]      = cp[e];
                out[2 * Bl + t]  = ol1 * cp[e];
                out[3 * Bl + t]  = olc * cp[e];
                out[4 * Bl + t]  = 0.0f;
                out[5 * Bl + t]  = 0.0f;
                out[6 * Bl + t]  = oo;
                out[7 * Bl + t]  = ol1;
                out[8 * Bl + t]  = olc;
                out[9 * Bl + t]  = f;
                out[10 * Bl + 2 * t]     = h;
                out[10 * Bl + 2 * t + 1] = ostd;
                out[12 * Bl + t] = ostd;
            }
        }
    }
}

// ---------------- host launch ----------------

extern "C" void kernel_launch(void* const* d_in, const int* in_sizes, int n_in,
                              void* d_out, int out_size, void* d_ws, size_t ws_size,
                              hipStream_t stream) {
    const float* x        = (const float*)d_in[0];
    // d_in[1] = epoch (unused)
    const int*   time_lag = (const int*)d_in[2];
    const float* y_obs    = (const float*)d_in[3];
    const float* c_mean   = (const float*)d_in[4];
    const float* c_std    = (const float*)d_in[5];
    const float* w_yom    = (const float*)d_in[6];
    const float* w_ylm    = (const float*)d_in[7];
    const float* w_yfm    = (const float*)d_in[8];
    const float* b0       = (const float*)d_in[9];
    const float* wb1      = (const float*)d_in[10];
    float* out = (float*)d_out;

    const int B = in_sizes[0] / 2;   // SEQ=1, IN=2

    double* part = (double*)d_ws;
    float*  stdp = (float*)((char*)d_ws + NPART * 2 * sizeof(double));

    partial_std_kernel<<<NPART, 256, 0, stream>>>(y_obs, part);
    final_std_kernel<<<1, 256, 0, stream>>>(part, stdp);

    // grid sized for tl=0 worst case; blocks past the active range self-disable
    const int blocks = (B + RPB - 1) / RPB;          // 489 for B = 2e6
    scan_kernel<<<blocks, BLK, 0, stream>>>(x, time_lag, c_mean, c_std,
                                            w_yom, w_ylm, w_yfm, b0, wb1,
                                            stdp, out, B);
}

// Round 4
// 175.021 us; speedup vs baseline: 1.4752x; 1.2412x over previous
//
#include <hip/hip_runtime.h>
#include <math.h>

#define SPIN 365
#define TRAIN 1000000
#define WARM 256
#define L 16                    // output rows per thread
#define BLK 256                 // threads per block
#define RPB (L * BLK)           // rows per block = 4096
#define NSTAGE (RPB + WARM)     // staged x rows per block = 4352
#define NPART 256

typedef float nt_f4 __attribute__((ext_vector_type(4)));   // native vec for NT stores

__device__ __forceinline__ void nt_store4(float* p, float a, float b, float c, float d) {
    nt_f4 v = {a, b, c, d};
    __builtin_nontemporal_store(v, (nt_f4*)p);
}

// ---------------- obsstd partial reduction (double precision) ----------------

__global__ void partial_std_kernel(const float* __restrict__ y, double* __restrict__ part) {
    int tid = blockIdx.x * blockDim.x + threadIdx.x;
    int stride = gridDim.x * blockDim.x;
    double s = 0.0, s2 = 0.0;
    for (int i = SPIN + tid; i < TRAIN; i += stride) {
        double v = (double)y[i];
        s += v;
        s2 += v * v;
    }
    for (int off = 32; off > 0; off >>= 1) {
        s  += __shfl_down(s,  off, 64);
        s2 += __shfl_down(s2, off, 64);
    }
    __shared__ double ls[4], ls2[4];
    int lane = threadIdx.x & 63, w = threadIdx.x >> 6;
    if (lane == 0) { ls[w] = s; ls2[w] = s2; }
    __syncthreads();
    if (threadIdx.x == 0) {
        double ts = 0.0, ts2 = 0.0;
        int nw = blockDim.x >> 6;
        for (int i = 0; i < nw; ++i) { ts += ls[i]; ts2 += ls2[i]; }
        part[2 * blockIdx.x]     = ts;
        part[2 * blockIdx.x + 1] = ts2;
    }
}

// ---------------- main chunk-parallel scan ----------------

struct Par { float oo1, ol1, kz1, kz0; };

__device__ __forceinline__ void gates(float c, float u2, const Par p,
                                      float& oo, float& olc, float& f) {
    float z  = fmaf(c, p.kz1, p.kz0);               // b0 + (c - mo)*wb1/so
    float e  = __expf(-z);
    float sg = __builtin_amdgcn_rcpf(1.0f + e);     // sigmoid(z)
    oo = p.oo1 * sg;
    float rc = __builtin_amdgcn_rcpf(c);
    float q  = u2 * rc;
    float olc_pos = fminf(p.ol1, q);                // ol1 - relu(ol1 - u2/c)
    olc = (c > 0.0f) ? olc_pos : p.ol1;
    f = 1.0f - oo - olc;
}

// LDS x layout: interleaved (u1,u2) with +1 dword pad per 16 rows.
// idx(off) = 2*off + (off>>4). Phase-A lanes (row stride 16) hit idx stride 33
// -> conflict-free; ds_read2_b32 fetches the pair in one instruction.
__device__ __forceinline__ void ldu(const float* __restrict__ up, int off,
                                    float& a, float& b) {
    if (off > NSTAGE - 1) off = NSTAGE - 1;         // clamped slots are never consumed
    int idx = 2 * off + (off >> 4);
    a = up[idx];
    b = up[idx + 1];
}

__global__ __launch_bounds__(BLK, 2)
void scan_kernel(const float* __restrict__ x,
                 const int*  __restrict__ time_lag_p,
                 const float* __restrict__ cm, const float* __restrict__ cs,
                 const float* __restrict__ wro, const float* __restrict__ wrl,
                 const float* __restrict__ wrf, const float* __restrict__ b0p,
                 const float* __restrict__ wb1p,
                 const double* __restrict__ part,
                 float* __restrict__ out, int Btot) {
    __shared__ float s_x[2 * NSTAGE + NSTAGE / 16];   // 35904 B
    __shared__ float s_cpre[BLK * (L + 1)];           // 17408 B
    __shared__ float s_ostd;

    const long long Bl = (long long)Btot;
    const int tl  = time_lag_p[0];
    const int tid = threadIdx.x;

    // rows b < time_lag: all outputs zero (no-op when tl == 0)
    {
        long long gstride = (long long)gridDim.x * BLK;
        for (long long b = (long long)blockIdx.x * BLK + tid; b < tl; b += gstride) {
            for (int s = 0; s < 10; ++s) out[(long long)s * Bl + b] = 0.0f;
            out[10 * Bl + 2 * b]     = 0.0f;
            out[10 * Bl + 2 * b + 1] = 0.0f;
            out[12 * Bl + b] = 0.0f;
        }
    }

    // uniform scalars
    const float wo = wro[0], wl = wrl[0], wf = wrf[0];
    const float b0 = b0p[0], wb1 = wb1p[0], mo = cm[0], so = cs[0];
    const float eo = __expf(wo), el = __expf(wl), ef = __expf(wf);
    const float denom = eo + el + ef;
    Par par;
    par.oo1 = eo / denom;
    par.ol1 = el / denom;
    par.kz1 = wb1 / so;
    par.kz0 = b0 - mo * par.kz1;
    const float ol1 = par.ol1;

    const long long row0   = (long long)tl + (long long)blockIdx.x * RPB;
    const long long base   = row0 - WARM;             // first staged row (may be < 0)
    const long long lastrow = Bl - 1;

    // ---------------- stage x window into LDS (coalesced) ----------------
    #pragma unroll
    for (int k = 0; k < NSTAGE / BLK; ++k) {          // 17 iterations
        int off = k * BLK + tid;
        long long row = base + off;
        row = row < 0 ? 0 : (row > lastrow ? lastrow : row);
        float2 v = *(const float2*)(x + 2 * row);
        int idx = 2 * off + (off >> 4);
        s_x[idx]     = v.x;
        s_x[idx + 1] = v.y;
    }
    __syncthreads();

    // ---------------- wave 0: finish obsstd reduction (overlaps Phase A) ----
    if (tid < 64) {
        double s = 0.0, s2 = 0.0;
        for (int i = tid; i < NPART; i += 64) {
            s  += part[2 * i];
            s2 += part[2 * i + 1];
        }
        for (int off = 32; off > 0; off >>= 1) {
            s  += __shfl_down(s,  off, 64);
            s2 += __shfl_down(s2, off, 64);
        }
        if (tid == 0) {
            double n = (double)(TRAIN - SPIN);
            double var = (s2 - s * s / n) / (n - 1.0);
            s_ostd = (float)sqrt(var);
        }
    }

    // ---------------- Phase A: recurrence from LDS, c_pre -> LDS ----------
    {
        const long long r0 = row0 + (long long)tid * L;
        if (r0 < Bl) {
            long long wstart = r0 - WARM;
            if (wstart < tl) wstart = tl;
            const int nwarm = (int)(r0 - wstart);      // always a multiple of 8
            long long lenl = Bl - r0;
            const int len = lenl > L ? L : (int)lenl;
            const int off0 = (int)(wstart - base);

            float c = 0.0f;                            // exact if wstart==tl
            // warm loop, groups of 8 with one-group-ahead prefetch
            if (nwarm > 0) {
                float ca[8], cb[8];
                #pragma unroll
                for (int q = 0; q < 8; ++q) ldu(s_x, off0 + q, ca[q], cb[q]);
                for (int s = 0; s < nwarm; s += 8) {
                    float na[8], nb[8];
                    #pragma unroll
                    for (int q = 0; q < 8; ++q) ldu(s_x, off0 + s + 8 + q, na[q], nb[q]);
                    #pragma unroll
                    for (int q = 0; q < 8; ++q) {
                        float oo, olc, f;
                        gates(c, cb[q], par, oo, olc, f);
                        c = fmaf(f, c, ca[q]);
                    }
                    #pragma unroll
                    for (int q = 0; q < 8; ++q) { ca[q] = na[q]; cb[q] = nb[q]; }
                }
            }
            // output loop (<= 16 steps): store pre-update c
            float oa[L], ob[L];
            #pragma unroll
            for (int q = 0; q < L; ++q) ldu(s_x, off0 + nwarm + q, oa[q], ob[q]);
            float* myld = s_cpre + tid * (L + 1);
            #pragma unroll
            for (int j = 0; j < L; ++j) {
                if (j < len) {
                    myld[j] = c;
                    float oo, olc, f;
                    gates(c, ob[j], par, oo, olc, f);
                    c = fmaf(f, c, oa[j]);
                }
            }
        }
    }

    __syncthreads();

    // ---------------- Phase B: re-derive gates, coalesced NT stores -------
    const float ostd = s_ostd;
    const bool aligned = ((tl & 3) == 0);

    #pragma unroll
    for (int p = 0; p < L / 4; ++p) {
        const int rl = p * (BLK * 4) + tid * 4;        // local row (multiple of 4)
        const long long r = row0 + rl;
        if (r >= Bl) continue;

        float cp[4], u2v[4];
        #pragma unroll
        for (int e = 0; e < 4; ++e) {
            int rle = rl + e;
            cp[e] = s_cpre[(rle >> 4) * (L + 1) + (rle & 15)];
            float ua, ub;
            ldu(s_x, rl + e + WARM, ua, ub);
            u2v[e] = ub;
        }

        if (aligned && (r + 3 < Bl)) {
            float h[4], lo[4], lc[4], go[4], gc[4], gf[4];
            #pragma unroll
            for (int e = 0; e < 4; ++e) {
                float oo, olc, f;
                gates(cp[e], u2v[e], par, oo, olc, f);
                h[e]  = oo * cp[e];
                lo[e] = ol1 * cp[e];
                lc[e] = olc * cp[e];
                go[e] = oo;
                gc[e] = olc;
                gf[e] = f;
            }
            nt_store4(out + r,          h[0], h[1], h[2], h[3]);
            nt_store4(out + Bl + r,     cp[0], cp[1], cp[2], cp[3]);
            nt_store4(out + 2 * Bl + r, lo[0], lo[1], lo[2], lo[3]);
            nt_store4(out + 3 * Bl + r, lc[0], lc[1], lc[2], lc[3]);
            nt_store4(out + 4 * Bl + r, 0.0f, 0.0f, 0.0f, 0.0f);
            nt_store4(out + 5 * Bl + r, 0.0f, 0.0f, 0.0f, 0.0f);
            nt_store4(out + 6 * Bl + r, go[0], go[1], go[2], go[3]);
            nt_store4(out + 7 * Bl + r, ol1, ol1, ol1, ol1);
            nt_store4(out + 8 * Bl + r, gc[0], gc[1], gc[2], gc[3]);
            nt_store4(out + 9 * Bl + r, gf[0], gf[1], gf[2], gf[3]);
            nt_store4(out + 10 * Bl + 2 * r,     h[0], ostd, h[1], ostd);
            nt_store4(out + 10 * Bl + 2 * r + 4, h[2], ostd, h[3], ostd);
            nt_store4(out + 12 * Bl + r, ostd, ostd, ostd, ostd);
        } else {
            #pragma unroll
            for (int e = 0; e < 4; ++e) {
                long long t = r + e;
                if (t >= Bl) break;
                float oo, olc, f;
                gates(cp[e], u2v[e], par, oo, olc, f);
                float h = oo * cp[e];
                out[t]           = h;
                out[Bl + t]      = cp[e];
                out[2 * Bl + t]  = ol1 * cp[e];
                out[3 * Bl + t]  = olc * cp[e];
                out[4 * Bl + t]  = 0.0f;
                out[5 * Bl + t]  = 0.0f;
                out[6 * Bl + t]  = oo;
                out[7 * Bl + t]  = ol1;
                out[8 * Bl + t]  = olc;
                out[9 * Bl + t]  = f;
                out[10 * Bl + 2 * t]     = h;
                out[10 * Bl + 2 * t + 1] = ostd;
                out[12 * Bl + t] = ostd;
            }
        }
    }
}

// ---------------- host launch ----------------

extern "C" void kernel_launch(void* const* d_in, const int* in_sizes, int n_in,
                              void* d_out, int out_size, void* d_ws, size_t ws_size,
                              hipStream_t stream) {
    const float* x        = (const float*)d_in[0];
    // d_in[1] = epoch (unused)
    const int*   time_lag = (const int*)d_in[2];
    const float* y_obs    = (const float*)d_in[3];
    const float* c_mean   = (const float*)d_in[4];
    const float* c_std    = (const float*)d_in[5];
    const float* w_yom    = (const float*)d_in[6];
    const float* w_ylm    = (const float*)d_in[7];
    const float* w_yfm    = (const float*)d_in[8];
    const float* b0       = (const float*)d_in[9];
    const float* wb1      = (const float*)d_in[10];
    float* out = (float*)d_out;

    const int B = in_sizes[0] / 2;   // SEQ=1, IN=2

    double* part = (double*)d_ws;

    partial_std_kernel<<<NPART, 256, 0, stream>>>(y_obs, part);

    const int blocks = (B + RPB - 1) / RPB;          // 489 for B = 2e6
    scan_kernel<<<blocks, BLK, 0, stream>>>(x, time_lag, c_mean, c_std,
                                            w_yom, w_ylm, w_yfm, b0, wb1,
                                            part, out, B);
}

// Round 5
// 163.012 us; speedup vs baseline: 1.5838x; 1.0737x over previous
//
#include <hip/hip_runtime.h>
#include <math.h>

#define SPIN 365
#define TRAIN 1000000
#define WARM 256
#define L 16                    // output rows per thread
#define BLK 256                 // threads per block
#define RPB (L * BLK)           // rows per block = 4096
#define NSTAGE (RPB + WARM)     // staged x rows per block = 4352
#define NPART 256

// ---------------- obsstd partial reduction (double precision) ----------------

__global__ void partial_std_kernel(const float* __restrict__ y, double* __restrict__ part) {
    int tid = blockIdx.x * blockDim.x + threadIdx.x;
    int stride = gridDim.x * blockDim.x;
    double s = 0.0, s2 = 0.0;
    for (int i = SPIN + tid; i < TRAIN; i += stride) {
        double v = (double)y[i];
        s += v;
        s2 += v * v;
    }
    for (int off = 32; off > 0; off >>= 1) {
        s  += __shfl_down(s,  off, 64);
        s2 += __shfl_down(s2, off, 64);
    }
    __shared__ double ls[4], ls2[4];
    int lane = threadIdx.x & 63, w = threadIdx.x >> 6;
    if (lane == 0) { ls[w] = s; ls2[w] = s2; }
    __syncthreads();
    if (threadIdx.x == 0) {
        double ts = 0.0, ts2 = 0.0;
        int nw = blockDim.x >> 6;
        for (int i = 0; i < nw; ++i) { ts += ls[i]; ts2 += ls2[i]; }
        part[2 * blockIdx.x]     = ts;
        part[2 * blockIdx.x + 1] = ts2;
    }
}

// ---------------- main chunk-parallel scan ----------------

struct Par { float oo1, ol1, kz1, kz0; };

__device__ __forceinline__ void gates(float c, float u2, const Par p,
                                      float& oo, float& olc, float& f) {
    float z  = fmaf(c, p.kz1, p.kz0);               // b0 + (c - mo)*wb1/so
    float e  = __expf(-z);
    float sg = __builtin_amdgcn_rcpf(1.0f + e);     // sigmoid(z)
    oo = p.oo1 * sg;
    float rc = __builtin_amdgcn_rcpf(c);
    float q  = u2 * rc;
    float olc_pos = fminf(p.ol1, q);                // ol1 - relu(ol1 - u2/c)
    olc = (c > 0.0f) ? olc_pos : p.ol1;
    f = 1.0f - oo - olc;
}

// LDS x layout: interleaved (u1,u2) with +1 dword pad per 16 rows.
// idx(off) = 2*off + (off>>4). Phase-A lanes (row stride 16) hit idx stride 33
// -> conflict-free; ds_read2_b32 fetches the pair in one instruction.
// All offsets are provably < NSTAGE (max off0+nwarm+15 = 4351) -> no clamp.
__device__ __forceinline__ void ldu(const float* __restrict__ up, int off,
                                    float& a, float& b) {
    int idx = 2 * off + (off >> 4);
    a = up[idx];
    b = up[idx + 1];
}

__global__ __launch_bounds__(BLK, 2)
void scan_kernel(const float* __restrict__ x,
                 const int*  __restrict__ time_lag_p,
                 const float* __restrict__ cm, const float* __restrict__ cs,
                 const float* __restrict__ wro, const float* __restrict__ wrl,
                 const float* __restrict__ wrf, const float* __restrict__ b0p,
                 const float* __restrict__ wb1p,
                 const double* __restrict__ part,
                 float* __restrict__ out, int Btot) {
    __shared__ float s_x[2 * NSTAGE + NSTAGE / 16];   // 35904 B
    __shared__ float s_cpre[BLK * (L + 1)];           // 17408 B
    __shared__ float s_ostd;

    const long long Bl = (long long)Btot;
    const int tl  = time_lag_p[0];
    const int tid = threadIdx.x;

    // rows b < time_lag: all outputs zero (no-op when tl == 0)
    {
        long long gstride = (long long)gridDim.x * BLK;
        for (long long b = (long long)blockIdx.x * BLK + tid; b < tl; b += gstride) {
            for (int s = 0; s < 10; ++s) out[(long long)s * Bl + b] = 0.0f;
            out[10 * Bl + 2 * b]     = 0.0f;
            out[10 * Bl + 2 * b + 1] = 0.0f;
            out[12 * Bl + b] = 0.0f;
        }
    }

    // uniform scalars
    const float wo = wro[0], wl = wrl[0], wf = wrf[0];
    const float b0 = b0p[0], wb1 = wb1p[0], mo = cm[0], so = cs[0];
    const float eo = __expf(wo), el = __expf(wl), ef = __expf(wf);
    const float denom = eo + el + ef;
    Par par;
    par.oo1 = eo / denom;
    par.ol1 = el / denom;
    par.kz1 = wb1 / so;
    par.kz0 = b0 - mo * par.kz1;
    const float ol1 = par.ol1;

    const long long row0    = (long long)tl + (long long)blockIdx.x * RPB;
    const long long base    = row0 - WARM;            // first staged row (may be < 0)
    const long long lastrow = Bl - 1;

    // ---------------- stage x window into LDS (coalesced) ----------------
    #pragma unroll
    for (int k = 0; k < NSTAGE / BLK; ++k) {          // 17 iterations
        int off = k * BLK + tid;
        long long row = base + off;
        row = row < 0 ? 0 : (row > lastrow ? lastrow : row);
        float2 v = *(const float2*)(x + 2 * row);
        int idx = 2 * off + (off >> 4);
        s_x[idx]     = v.x;
        s_x[idx + 1] = v.y;
    }
    __syncthreads();

    // ---------------- wave 0: finish obsstd reduction (overlaps Phase A) ----
    if (tid < 64) {
        double s = 0.0, s2 = 0.0;
        for (int i = tid; i < NPART; i += 64) {
            s  += part[2 * i];
            s2 += part[2 * i + 1];
        }
        for (int off = 32; off > 0; off >>= 1) {
            s  += __shfl_down(s,  off, 64);
            s2 += __shfl_down(s2, off, 64);
        }
        if (tid == 0) {
            double n = (double)(TRAIN - SPIN);
            double var = (s2 - s * s / n) / (n - 1.0);
            s_ostd = (float)sqrt(var);
        }
    }

    // ---------------- Phase A: recurrence from LDS, c_pre -> LDS ----------
    {
        const long long r0 = row0 + (long long)tid * L;
        if (r0 < Bl) {
            long long wstart = r0 - WARM;
            if (wstart < tl) wstart = tl;
            const int nwarm = (int)(r0 - wstart);      // multiple of 16
            long long lenl = Bl - r0;
            const int len = lenl > L ? L : (int)lenl;
            const int off0 = (int)(wstart - base);

            float c = 0.0f;                            // exact if wstart==tl
            float aA[8], bA[8], aB[8], bB[8];
            #pragma unroll
            for (int q = 0; q < 8; ++q) ldu(s_x, off0 + q, aA[q], bA[q]);

            // warm loop: ping-pong, 16 steps/iter, prefetch one group ahead
            for (int s = 0; s < nwarm; s += 16) {
                #pragma unroll
                for (int q = 0; q < 8; ++q) ldu(s_x, off0 + s + 8 + q, aB[q], bB[q]);
                #pragma unroll
                for (int q = 0; q < 8; ++q) {
                    float oo, olc, f;
                    gates(c, bA[q], par, oo, olc, f);
                    c = fmaf(f, c, aA[q]);
                }
                #pragma unroll
                for (int q = 0; q < 8; ++q) ldu(s_x, off0 + s + 16 + q, aA[q], bA[q]);
                #pragma unroll
                for (int q = 0; q < 8; ++q) {
                    float oo, olc, f;
                    gates(c, bB[q], par, oo, olc, f);
                    c = fmaf(f, c, aB[q]);
                }
            }
            // A now holds rows [nwarm, nwarm+8); load the second output group
            #pragma unroll
            for (int q = 0; q < 8; ++q) ldu(s_x, off0 + nwarm + 8 + q, aB[q], bB[q]);

            float* myld = s_cpre + tid * (L + 1);
            #pragma unroll
            for (int j = 0; j < 8; ++j) {
                if (j < len) myld[j] = c;              // pre-update state
                float oo, olc, f;
                gates(c, bA[j], par, oo, olc, f);
                c = fmaf(f, c, aA[j]);
            }
            #pragma unroll
            for (int j = 0; j < 8; ++j) {
                if (j + 8 < len) myld[j + 8] = c;
                float oo, olc, f;
                gates(c, bB[j], par, oo, olc, f);
                c = fmaf(f, c, aB[j]);
            }
        }
    }

    __syncthreads();

    // ---------------- Phase B: re-derive gates, coalesced stores ----------
    const float ostd = s_ostd;
    const bool aligned = ((tl & 3) == 0);
    const float4 z4  = make_float4(0.0f, 0.0f, 0.0f, 0.0f);
    const float4 ol4 = make_float4(ol1, ol1, ol1, ol1);
    const float4 os4 = make_float4(ostd, ostd, ostd, ostd);

    #pragma unroll
    for (int p = 0; p < L / 4; ++p) {
        const int rl = p * (BLK * 4) + tid * 4;        // local row (multiple of 4)
        const long long r = row0 + rl;
        if (r >= Bl) continue;

        float cp[4], u2v[4];
        #pragma unroll
        for (int e = 0; e < 4; ++e) {
            int rle = rl + e;
            cp[e] = s_cpre[(rle >> 4) * (L + 1) + (rle & 15)];
            float ua, ub;
            ldu(s_x, rl + e + WARM, ua, ub);
            u2v[e] = ub;
        }

        if (aligned && (r + 3 < Bl)) {
            float h[4], lo[4], lc[4], go[4], gc[4], gf[4];
            #pragma unroll
            for (int e = 0; e < 4; ++e) {
                float oo, olc, f;
                gates(cp[e], u2v[e], par, oo, olc, f);
                h[e]  = oo * cp[e];
                lo[e] = ol1 * cp[e];
                lc[e] = olc * cp[e];
                go[e] = oo;
                gc[e] = olc;
                gf[e] = f;
            }
            *(float4*)(out + r)          = make_float4(h[0], h[1], h[2], h[3]);
            *(float4*)(out + Bl + r)     = make_float4(cp[0], cp[1], cp[2], cp[3]);
            *(float4*)(out + 2 * Bl + r) = make_float4(lo[0], lo[1], lo[2], lo[3]);
            *(float4*)(out + 3 * Bl + r) = make_float4(lc[0], lc[1], lc[2], lc[3]);
            *(float4*)(out + 4 * Bl + r) = z4;
            *(float4*)(out + 5 * Bl + r) = z4;
            *(float4*)(out + 6 * Bl + r) = make_float4(go[0], go[1], go[2], go[3]);
            *(float4*)(out + 7 * Bl + r) = ol4;
            *(float4*)(out + 8 * Bl + r) = make_float4(gc[0], gc[1], gc[2], gc[3]);
            *(float4*)(out + 9 * Bl + r) = make_float4(gf[0], gf[1], gf[2], gf[3]);
            *(float4*)(out + 10 * Bl + 2 * r)     = make_float4(h[0], ostd, h[1], ostd);
            *(float4*)(out + 10 * Bl + 2 * r + 4) = make_float4(h[2], ostd, h[3], ostd);
            *(float4*)(out + 12 * Bl + r) = os4;
        } else {
            #pragma unroll
            for (int e = 0; e < 4; ++e) {
                long long t = r + e;
                if (t >= Bl) break;
                float oo, olc, f;
                gates(cp[e], u2v[e], par, oo, olc, f);
                float h = oo * cp[e];
                out[t]           = h;
                out[Bl + t]      = cp[e];
                out[2 * Bl + t]  = ol1 * cp[e];
                out[3 * Bl + t]  = olc * cp[e];
                out[4 * Bl + t]  = 0.0f;
                out[5 * Bl + t]  = 0.0f;
                out[6 * Bl + t]  = oo;
                out[7 * Bl + t]  = ol1;
                out[8 * Bl + t]  = olc;
                out[9 * Bl + t]  = f;
                out[10 * Bl + 2 * t]     = h;
                out[10 * Bl + 2 * t + 1] = ostd;
                out[12 * Bl + t] = ostd;
            }
        }
    }
}

// ---------------- host launch ----------------

extern "C" void kernel_launch(void* const* d_in, const int* in_sizes, int n_in,
                              void* d_out, int out_size, void* d_ws, size_t ws_size,
                              hipStream_t stream) {
    const float* x        = (const float*)d_in[0];
    // d_in[1] = epoch (unused)
    const int*   time_lag = (const int*)d_in[2];
    const float* y_obs    = (const float*)d_in[3];
    const float* c_mean   = (const float*)d_in[4];
    const float* c_std    = (const float*)d_in[5];
    const float* w_yom    = (const float*)d_in[6];
    const float* w_ylm    = (const float*)d_in[7];
    const float* w_yfm    = (const float*)d_in[8];
    const float* b0       = (const float*)d_in[9];
    const float* wb1      = (const float*)d_in[10];
    float* out = (float*)d_out;

    const int B = in_sizes[0] / 2;   // SEQ=1, IN=2

    double* part = (double*)d_ws;

    partial_std_kernel<<<NPART, 256, 0, stream>>>(y_obs, part);

    const int blocks = (B + RPB - 1) / RPB;          // 489 for B = 2e6
    scan_kernel<<<blocks, BLK, 0, stream>>>(x, time_lag, c_mean, c_std,
                                            w_yom, w_ylm, w_yfm, b0, wb1,
                                            part, out, B);
}

// Round 6
// 158.896 us; speedup vs baseline: 1.6249x; 1.0259x over previous
//
#include <hip/hip_runtime.h>
#include <math.h>

#define SPIN 365
#define TRAIN 1000000
#define WARM 128
#define L 16                    // output rows per thread
#define BLK 256                 // threads per block
#define RPB (L * BLK)           // rows per block = 4096
#define NSTAGE (RPB + WARM)     // staged x rows per block = 4224
#define NPART 256

// ---------------- obsstd partial reduction (double precision) ----------------

__global__ void partial_std_kernel(const float* __restrict__ y, double* __restrict__ part) {
    int tid = blockIdx.x * blockDim.x + threadIdx.x;
    int stride = gridDim.x * blockDim.x;
    double s = 0.0, s2 = 0.0;
    for (int i = SPIN + tid; i < TRAIN; i += stride) {
        double v = (double)y[i];
        s += v;
        s2 += v * v;
    }
    for (int off = 32; off > 0; off >>= 1) {
        s  += __shfl_down(s,  off, 64);
        s2 += __shfl_down(s2, off, 64);
    }
    __shared__ double ls[4], ls2[4];
    int lane = threadIdx.x & 63, w = threadIdx.x >> 6;
    if (lane == 0) { ls[w] = s; ls2[w] = s2; }
    __syncthreads();
    if (threadIdx.x == 0) {
        double ts = 0.0, ts2 = 0.0;
        int nw = blockDim.x >> 6;
        for (int i = 0; i < nw; ++i) { ts += ls[i]; ts2 += ls2[i]; }
        part[2 * blockIdx.x]     = ts;
        part[2 * blockIdx.x + 1] = ts2;
    }
}

// ---------------- main chunk-parallel scan ----------------

// ez1/ez0: -(wb1/so)*log2e and -(b0 - mo*wb1/so)*log2e, so exp2(fma(c,ez1,ez0))
// = exp(-z) with one fewer full-rate mul than __expf.
struct Par { float oo1, ol1, ez1, ez0; };

// State update only (no per-gate outputs): algebraically identical to
// c' = (1-oo-olc)c + u1 but multiplies the min through by c, removing rcp(c).
// 2 transcendentals (exp2, rcp) instead of 3.
__device__ __forceinline__ void step_state(float& c, float u1, float u2, const Par p) {
    float e   = __builtin_amdgcn_exp2f(fmaf(c, p.ez1, p.ez0));  // exp(-z)
    float sg  = __builtin_amdgcn_rcpf(1.0f + e);                // sigmoid(z)
    float ooc = p.oo1 * sg * c;                                 // oo * c
    float lc  = p.ol1 * c;
    float mlc = (c > 0.0f) ? fminf(lc, u2) : lc;                // olc * c
    c = c - ooc - mlc + u1;
}

// Full gates for Phase B (matches reference formulation per-output).
__device__ __forceinline__ void gates(float c, float u2, const Par p,
                                      float& oo, float& olc, float& f) {
    float e  = __builtin_amdgcn_exp2f(fmaf(c, p.ez1, p.ez0));
    float sg = __builtin_amdgcn_rcpf(1.0f + e);
    oo = p.oo1 * sg;
    float rc = __builtin_amdgcn_rcpf(c);
    float q  = u2 * rc;
    float olc_pos = fminf(p.ol1, q);               // ol1 - relu(ol1 - u2/c)
    olc = (c > 0.0f) ? olc_pos : p.ol1;
    f = 1.0f - oo - olc;
}

// LDS x layout: interleaved (u1,u2) with +1 dword pad per 16 rows.
// idx(off) = 2*off + (off>>4). Phase-A lanes (row stride 16) hit idx stride 33
// -> conflict-free; pair read is one ds_read2_b32. All consumed offsets are
// provably < NSTAGE -> no clamp.
__device__ __forceinline__ void ldu(const float* __restrict__ up, int off,
                                    float& a, float& b) {
    int idx = 2 * off + (off >> 4);
    a = up[idx];
    b = up[idx + 1];
}

__global__ __launch_bounds__(BLK, 2)
void scan_kernel(const float* __restrict__ x,
                 const int*  __restrict__ time_lag_p,
                 const float* __restrict__ cm, const float* __restrict__ cs,
                 const float* __restrict__ wro, const float* __restrict__ wrl,
                 const float* __restrict__ wrf, const float* __restrict__ b0p,
                 const float* __restrict__ wb1p,
                 const double* __restrict__ part,
                 float* __restrict__ out, int Btot) {
    __shared__ float s_x[2 * NSTAGE + NSTAGE / 16];   // 34848 B
    __shared__ float s_cpre[BLK * (L + 1)];           // 17408 B
    __shared__ float s_ostd;

    const long long Bl = (long long)Btot;
    const int tl  = time_lag_p[0];
    const int tid = threadIdx.x;

    // rows b < time_lag: all outputs zero (no-op when tl == 0)
    {
        long long gstride = (long long)gridDim.x * BLK;
        for (long long b = (long long)blockIdx.x * BLK + tid; b < tl; b += gstride) {
            for (int s = 0; s < 10; ++s) out[(long long)s * Bl + b] = 0.0f;
            out[10 * Bl + 2 * b]     = 0.0f;
            out[10 * Bl + 2 * b + 1] = 0.0f;
            out[12 * Bl + b] = 0.0f;
        }
    }

    // uniform scalars
    const float wo = wro[0], wl = wrl[0], wf = wrf[0];
    const float b0 = b0p[0], wb1 = wb1p[0], mo = cm[0], so = cs[0];
    const float eo = __expf(wo), el = __expf(wl), ef = __expf(wf);
    const float denom = eo + el + ef;
    const float kz1 = wb1 / so;
    const float kz0 = b0 - mo * kz1;
    const float LOG2E = 1.4426950408889634f;
    Par par;
    par.oo1 = eo / denom;
    par.ol1 = el / denom;
    par.ez1 = -kz1 * LOG2E;
    par.ez0 = -kz0 * LOG2E;
    const float ol1 = par.ol1;

    const long long row0    = (long long)tl + (long long)blockIdx.x * RPB;
    const long long base    = row0 - WARM;            // first staged row (may be < 0)
    const long long lastrow = Bl - 1;

    // ---------------- stage x window into LDS (coalesced) ----------------
    #pragma unroll
    for (int k = 0; k < (NSTAGE + BLK - 1) / BLK; ++k) {   // 17 iterations (last half)
        int off = k * BLK + tid;
        if (off < NSTAGE) {
            long long row = base + off;
            row = row < 0 ? 0 : (row > lastrow ? lastrow : row);
            float2 v = *(const float2*)(x + 2 * row);
            int idx = 2 * off + (off >> 4);
            s_x[idx]     = v.x;
            s_x[idx + 1] = v.y;
        }
    }
    __syncthreads();

    // ---------------- wave 0: finish obsstd reduction (overlaps Phase A) ----
    if (tid < 64) {
        double s = 0.0, s2 = 0.0;
        for (int i = tid; i < NPART; i += 64) {
            s  += part[2 * i];
            s2 += part[2 * i + 1];
        }
        for (int off = 32; off > 0; off >>= 1) {
            s  += __shfl_down(s,  off, 64);
            s2 += __shfl_down(s2, off, 64);
        }
        if (tid == 0) {
            double n = (double)(TRAIN - SPIN);
            double var = (s2 - s * s / n) / (n - 1.0);
            s_ostd = (float)sqrt(var);
        }
    }

    // ---------------- Phase A: recurrence from LDS, c_pre -> LDS ----------
    {
        const long long r0 = row0 + (long long)tid * L;
        if (r0 < Bl) {
            long long wstart = r0 - WARM;
            if (wstart < tl) wstart = tl;
            const int nwarm = (int)(r0 - wstart);      // multiple of 16
            long long lenl = Bl - r0;
            const int len = lenl > L ? L : (int)lenl;
            const int off0 = (int)(wstart - base);

            float c = 0.0f;                            // exact if wstart==tl
            float aA[8], bA[8], aB[8], bB[8];
            #pragma unroll
            for (int q = 0; q < 8; ++q) ldu(s_x, off0 + q, aA[q], bA[q]);

            // warm loop: ping-pong, 16 steps/iter, prefetch one group ahead
            for (int s = 0; s < nwarm; s += 16) {
                #pragma unroll
                for (int q = 0; q < 8; ++q) ldu(s_x, off0 + s + 8 + q, aB[q], bB[q]);
                #pragma unroll
                for (int q = 0; q < 8; ++q) step_state(c, aA[q], bA[q], par);
                #pragma unroll
                for (int q = 0; q < 8; ++q) ldu(s_x, off0 + s + 16 + q, aA[q], bA[q]);
                #pragma unroll
                for (int q = 0; q < 8; ++q) step_state(c, aB[q], bB[q], par);
            }
            // A now holds rows [nwarm, nwarm+8); load the second output group
            #pragma unroll
            for (int q = 0; q < 8; ++q) ldu(s_x, off0 + nwarm + 8 + q, aB[q], bB[q]);

            float* myld = s_cpre + tid * (L + 1);
            #pragma unroll
            for (int j = 0; j < 8; ++j) {
                if (j < len) myld[j] = c;              // pre-update state
                step_state(c, aA[j], bA[j], par);
            }
            #pragma unroll
            for (int j = 0; j < 8; ++j) {
                if (j + 8 < len) myld[j + 8] = c;
                step_state(c, aB[j], bB[j], par);
            }
        }
    }

    __syncthreads();

    // ---------------- Phase B: re-derive gates, coalesced stores ----------
    const float ostd = s_ostd;
    const bool aligned = ((tl & 3) == 0);
    const float4 z4  = make_float4(0.0f, 0.0f, 0.0f, 0.0f);
    const float4 ol4 = make_float4(ol1, ol1, ol1, ol1);
    const float4 os4 = make_float4(ostd, ostd, ostd, ostd);

    #pragma unroll
    for (int p = 0; p < L / 4; ++p) {
        const int rl = p * (BLK * 4) + tid * 4;        // local row (multiple of 4)
        const long long r = row0 + rl;
        if (r >= Bl) continue;

        float cp[4], u2v[4];
        #pragma unroll
        for (int e = 0; e < 4; ++e) {
            int rle = rl + e;
            cp[e] = s_cpre[(rle >> 4) * (L + 1) + (rle & 15)];
            float ua, ub;
            ldu(s_x, rl + e + WARM, ua, ub);
            u2v[e] = ub;
        }

        if (aligned && (r + 3 < Bl)) {
            float h[4], lo[4], lc[4], go[4], gc[4], gf[4];
            #pragma unroll
            for (int e = 0; e < 4; ++e) {
                float oo, olc, f;
                gates(cp[e], u2v[e], par, oo, olc, f);
                h[e]  = oo * cp[e];
                lo[e] = ol1 * cp[e];
                lc[e] = olc * cp[e];
                go[e] = oo;
                gc[e] = olc;
                gf[e] = f;
            }
            *(float4*)(out + r)          = make_float4(h[0], h[1], h[2], h[3]);
            *(float4*)(out + Bl + r)     = make_float4(cp[0], cp[1], cp[2], cp[3]);
            *(float4*)(out + 2 * Bl + r) = make_float4(lo[0], lo[1], lo[2], lo[3]);
            *(float4*)(out + 3 * Bl + r) = make_float4(lc[0], lc[1], lc[2], lc[3]);
            *(float4*)(out + 4 * Bl + r) = z4;
            *(float4*)(out + 5 * Bl + r) = z4;
            *(float4*)(out + 6 * Bl + r) = make_float4(go[0], go[1], go[2], go[3]);
            *(float4*)(out + 7 * Bl + r) = ol4;
            *(float4*)(out + 8 * Bl + r) = make_float4(gc[0], gc[1], gc[2], gc[3]);
            *(float4*)(out + 9 * Bl + r) = make_float4(gf[0], gf[1], gf[2], gf[3]);
            *(float4*)(out + 10 * Bl + 2 * r)     = make_float4(h[0], ostd, h[1], ostd);
            *(float4*)(out + 10 * Bl + 2 * r + 4) = make_float4(h[2], ostd, h[3], ostd);
            *(float4*)(out + 12 * Bl + r) = os4;
        } else {
            #pragma unroll
            for (int e = 0; e < 4; ++e) {
                long long t = r + e;
                if (t >= Bl) break;
                float oo, olc, f;
                gates(cp[e], u2v[e], par, oo, olc, f);
                float h = oo * cp[e];
                out[t]           = h;
                out[Bl + t]      = cp[e];
                out[2 * Bl + t]  = ol1 * cp[e];
                out[3 * Bl + t]  = olc * cp[e];
                out[4 * Bl + t]  = 0.0f;
                out[5 * Bl + t]  = 0.0f;
                out[6 * Bl + t]  = oo;
                out[7 * Bl + t]  = ol1;
                out[8 * Bl + t]  = olc;
                out[9 * Bl + t]  = f;
                out[10 * Bl + 2 * t]     = h;
                out[10 * Bl + 2 * t + 1] = ostd;
                out[12 * Bl + t] = ostd;
            }
        }
    }
}

// ---------------- host launch ----------------

extern "C" void kernel_launch(void* const* d_in, const int* in_sizes, int n_in,
                              void* d_out, int out_size, void* d_ws, size_t ws_size,
                              hipStream_t stream) {
    const float* x        = (const float*)d_in[0];
    // d_in[1] = epoch (unused)
    const int*   time_lag = (const int*)d_in[2];
    const float* y_obs    = (const float*)d_in[3];
    const float* c_mean   = (const float*)d_in[4];
    const float* c_std    = (const float*)d_in[5];
    const float* w_yom    = (const float*)d_in[6];
    const float* w_ylm    = (const float*)d_in[7];
    const float* w_yfm    = (const float*)d_in[8];
    const float* b0       = (const float*)d_in[9];
    const float* wb1      = (const float*)d_in[10];
    float* out = (float*)d_out;

    const int B = in_sizes[0] / 2;   // SEQ=1, IN=2

    double* part = (double*)d_ws;

    partial_std_kernel<<<NPART, 256, 0, stream>>>(y_obs, part);

    const int blocks = (B + RPB - 1) / RPB;          // 489 for B = 2e6
    scan_kernel<<<blocks, BLK, 0, stream>>>(x, time_lag, c_mean, c_std,
                                            w_yom, w_ylm, w_yfm, b0, wb1,
                                            part, out, B);
}

// Round 7
// 154.382 us; speedup vs baseline: 1.6724x; 1.0292x over previous
//
#include <hip/hip_runtime.h>
#include <math.h>

#define SPIN 365
#define TRAIN 1000000
#define WARM 64
#define L 8                     // output rows per thread
#define BLK 512                 // threads per block (8 waves)
#define RPB (L * BLK)           // rows per block = 4096
#define NSTAGE (RPB + WARM)     // staged x rows per block = 4160
#define NPART 256

// ---------------- obsstd partial reduction (double precision) ----------------

__global__ void partial_std_kernel(const float* __restrict__ y, double* __restrict__ part) {
    int tid = blockIdx.x * blockDim.x + threadIdx.x;
    int stride = gridDim.x * blockDim.x;
    double s = 0.0, s2 = 0.0;
    for (int i = SPIN + tid; i < TRAIN; i += stride) {
        double v = (double)y[i];
        s += v;
        s2 += v * v;
    }
    for (int off = 32; off > 0; off >>= 1) {
        s  += __shfl_down(s,  off, 64);
        s2 += __shfl_down(s2, off, 64);
    }
    __shared__ double ls[4], ls2[4];
    int lane = threadIdx.x & 63, w = threadIdx.x >> 6;
    if (lane == 0) { ls[w] = s; ls2[w] = s2; }
    __syncthreads();
    if (threadIdx.x == 0) {
        double ts = 0.0, ts2 = 0.0;
        int nw = blockDim.x >> 6;
        for (int i = 0; i < nw; ++i) { ts += ls[i]; ts2 += ls2[i]; }
        part[2 * blockIdx.x]     = ts;
        part[2 * blockIdx.x + 1] = ts2;
    }
}

// ---------------- main chunk-parallel scan ----------------

// ez1/ez0 fold -(z)*log2e so exp2(fma(c,ez1,ez0)) = exp(-z).
struct Par { float oo1, ol1, ez1, ez0; };

// State update only: c' = c - oo*c - olc*c + u1 with olc*c = c>0 ? min(ol1*c,u2)
// : ol1*c (algebraically identical, no rcp(c)). 2 transcendentals.
__device__ __forceinline__ void step_state(float& c, float u1, float u2, const Par p) {
    float e   = __builtin_amdgcn_exp2f(fmaf(c, p.ez1, p.ez0));  // exp(-z)
    float sg  = __builtin_amdgcn_rcpf(1.0f + e);                // sigmoid(z)
    float ooc = p.oo1 * sg * c;
    float lc  = p.ol1 * c;
    float mlc = (c > 0.0f) ? fminf(lc, u2) : lc;
    c = c - ooc - mlc + u1;
}

// Full gates for Phase B (matches reference formulation per-output).
__device__ __forceinline__ void gates(float c, float u2, const Par p,
                                      float& oo, float& olc, float& f) {
    float e  = __builtin_amdgcn_exp2f(fmaf(c, p.ez1, p.ez0));
    float sg = __builtin_amdgcn_rcpf(1.0f + e);
    oo = p.oo1 * sg;
    float rc = __builtin_amdgcn_rcpf(c);
    float q  = u2 * rc;
    float olc_pos = fminf(p.ol1, q);               // ol1 - relu(ol1 - u2/c)
    olc = (c > 0.0f) ? olc_pos : p.ol1;
    f = 1.0f - oo - olc;
}

// LDS x layout: interleaved (u1,u2), +1 dword pad per 16 rows.
// idx(off) = 2*off + (off>>4). Phase-A lanes (row stride 8) -> 2-way bank
// aliasing = free; pair read is one ds_read2_b32.
__device__ __forceinline__ void ldu(const float* __restrict__ up, int off,
                                    float& a, float& b) {
    int idx = 2 * off + (off >> 4);
    a = up[idx];
    b = up[idx + 1];
}

__global__ __launch_bounds__(BLK, 4)
void scan_kernel(const float* __restrict__ x,
                 const int*  __restrict__ time_lag_p,
                 const float* __restrict__ cm, const float* __restrict__ cs,
                 const float* __restrict__ wro, const float* __restrict__ wrl,
                 const float* __restrict__ wrf, const float* __restrict__ b0p,
                 const float* __restrict__ wb1p,
                 const double* __restrict__ part,
                 float* __restrict__ out, int Btot) {
    __shared__ float s_x[2 * NSTAGE + NSTAGE / 16];   // 34320 B
    __shared__ float s_cpre[BLK * (L + 1)];           // 18432 B (stride 9: conflict-free)
    __shared__ float s_ostd;

    const long long Bl = (long long)Btot;
    const int tl  = time_lag_p[0];
    const int tid = threadIdx.x;

    // rows b < time_lag: all outputs zero (no-op when tl == 0)
    {
        long long gstride = (long long)gridDim.x * BLK;
        for (long long b = (long long)blockIdx.x * BLK + tid; b < tl; b += gstride) {
            for (int s = 0; s < 10; ++s) out[(long long)s * Bl + b] = 0.0f;
            out[10 * Bl + 2 * b]     = 0.0f;
            out[10 * Bl + 2 * b + 1] = 0.0f;
            out[12 * Bl + b] = 0.0f;
        }
    }

    // uniform scalars
    const float wo = wro[0], wl = wrl[0], wf = wrf[0];
    const float b0 = b0p[0], wb1 = wb1p[0], mo = cm[0], so = cs[0];
    const float eo = __expf(wo), el = __expf(wl), ef = __expf(wf);
    const float denom = eo + el + ef;
    const float kz1 = wb1 / so;
    const float kz0 = b0 - mo * kz1;
    const float LOG2E = 1.4426950408889634f;
    Par par;
    par.oo1 = eo / denom;
    par.ol1 = el / denom;
    par.ez1 = -kz1 * LOG2E;
    par.ez0 = -kz0 * LOG2E;
    const float ol1 = par.ol1;

    const long long row0    = (long long)tl + (long long)blockIdx.x * RPB;
    const long long base    = row0 - WARM;            // first staged row (may be < tl)
    const long long lastrow = Bl - 1;

    // ---------------- stage x window into LDS (coalesced) ----------------
    #pragma unroll
    for (int k = 0; k < (NSTAGE + BLK - 1) / BLK; ++k) {   // 9 iterations
        int off = k * BLK + tid;
        if (off < NSTAGE) {
            long long row = base + off;
            row = row < 0 ? 0 : (row > lastrow ? lastrow : row);
            float2 v = *(const float2*)(x + 2 * row);
            int idx = 2 * off + (off >> 4);
            s_x[idx]     = v.x;
            s_x[idx + 1] = v.y;
        }
    }
    __syncthreads();

    // ---------------- wave 0: finish obsstd reduction (overlaps Phase A) ----
    if (tid < 64) {
        double s = 0.0, s2 = 0.0;
        for (int i = tid; i < NPART; i += 64) {
            s  += part[2 * i];
            s2 += part[2 * i + 1];
        }
        for (int off = 32; off > 0; off >>= 1) {
            s  += __shfl_down(s,  off, 64);
            s2 += __shfl_down(s2, off, 64);
        }
        if (tid == 0) {
            double n = (double)(TRAIN - SPIN);
            double var = (s2 - s * s / n) / (n - 1.0);
            s_ostd = (float)sqrt(var);
        }
    }

    // ---------------- Phase A: recurrence from LDS, c_pre -> LDS ----------
    {
        const long long r0 = row0 + (long long)tid * L;
        if (r0 < Bl) {
            long long wstart = r0 - WARM;
            if (wstart < tl) wstart = tl;
            const int nwarm = (int)(r0 - wstart);      // multiple of 8; ==WARM except
            long long lenl = Bl - r0;                  // block 0's first 8 threads
            const int len = lenl > L ? L : (int)lenl;
            const int off0 = (int)(wstart - base);

            float c = 0.0f;                            // exact if wstart==tl
            float aA[8], bA[8], aB[8], bB[8];

            if (nwarm == WARM) {                       // common path: off0 == tid*8
                #pragma unroll
                for (int q = 0; q < 8; ++q) ldu(s_x, off0 + q, aA[q], bA[q]);
                #pragma unroll
                for (int g = 0; g < 4; ++g) {          // 8 groups of 8 warm steps
                    #pragma unroll
                    for (int q = 0; q < 8; ++q) ldu(s_x, off0 + (2 * g + 1) * 8 + q, aB[q], bB[q]);
                    #pragma unroll
                    for (int q = 0; q < 8; ++q) step_state(c, aA[q], bA[q], par);
                    #pragma unroll
                    for (int q = 0; q < 8; ++q) ldu(s_x, off0 + (2 * g + 2) * 8 + q, aA[q], bA[q]);
                    #pragma unroll
                    for (int q = 0; q < 8; ++q) step_state(c, aB[q], bB[q], par);
                }
                // aA/bA now hold the 8 output rows (off0+64 .. off0+71)
            } else {                                   // block 0, tid < 8 only
                for (int s = 0; s < nwarm; ++s) {
                    float ua, ub;
                    ldu(s_x, off0 + s, ua, ub);
                    step_state(c, ua, ub, par);
                }
                #pragma unroll
                for (int q = 0; q < 8; ++q) ldu(s_x, off0 + nwarm + q, aA[q], bA[q]);
            }

            float* myld = s_cpre + tid * (L + 1);
            #pragma unroll
            for (int j = 0; j < L; ++j) {
                if (j < len) myld[j] = c;              // pre-update state
                step_state(c, aA[j], bA[j], par);
            }
        }
    }

    __syncthreads();

    // ---------------- Phase B: re-derive gates, coalesced stores ----------
    const float ostd = s_ostd;
    const bool aligned = ((tl & 3) == 0);
    const float4 z4  = make_float4(0.0f, 0.0f, 0.0f, 0.0f);
    const float4 ol4 = make_float4(ol1, ol1, ol1, ol1);
    const float4 os4 = make_float4(ostd, ostd, ostd, ostd);

    #pragma unroll
    for (int p = 0; p < L / 4; ++p) {                  // 2 iterations
        const int rl = p * (BLK * 4) + tid * 4;        // local row (multiple of 4)
        const long long r = row0 + rl;
        if (r >= Bl) continue;

        float cp[4], u2v[4];
        #pragma unroll
        for (int e = 0; e < 4; ++e) {
            int rle = rl + e;
            cp[e] = s_cpre[(rle >> 3) * (L + 1) + (rle & 7)];
            float ua, ub;
            ldu(s_x, rl + e + WARM, ua, ub);
            u2v[e] = ub;
        }

        if (aligned && (r + 3 < Bl)) {
            float h[4], lo[4], lc[4], go[4], gc[4], gf[4];
            #pragma unroll
            for (int e = 0; e < 4; ++e) {
                float oo, olc, f;
                gates(cp[e], u2v[e], par, oo, olc, f);
                h[e]  = oo * cp[e];
                lo[e] = ol1 * cp[e];
                lc[e] = olc * cp[e];
                go[e] = oo;
                gc[e] = olc;
                gf[e] = f;
            }
            *(float4*)(out + r)          = make_float4(h[0], h[1], h[2], h[3]);
            *(float4*)(out + Bl + r)     = make_float4(cp[0], cp[1], cp[2], cp[3]);
            *(float4*)(out + 2 * Bl + r) = make_float4(lo[0], lo[1], lo[2], lo[3]);
            *(float4*)(out + 3 * Bl + r) = make_float4(lc[0], lc[1], lc[2], lc[3]);
            *(float4*)(out + 4 * Bl + r) = z4;
            *(float4*)(out + 5 * Bl + r) = z4;
            *(float4*)(out + 6 * Bl + r) = make_float4(go[0], go[1], go[2], go[3]);
            *(float4*)(out + 7 * Bl + r) = ol4;
            *(float4*)(out + 8 * Bl + r) = make_float4(gc[0], gc[1], gc[2], gc[3]);
            *(float4*)(out + 9 * Bl + r) = make_float4(gf[0], gf[1], gf[2], gf[3]);
            *(float4*)(out + 10 * Bl + 2 * r)     = make_float4(h[0], ostd, h[1], ostd);
            *(float4*)(out + 10 * Bl + 2 * r + 4) = make_float4(h[2], ostd, h[3], ostd);
            *(float4*)(out + 12 * Bl + r) = os4;
        } else {
            #pragma unroll
            for (int e = 0; e < 4; ++e) {
                long long t = r + e;
                if (t >= Bl) break;
                float oo, olc, f;
                gates(cp[e], u2v[e], par, oo, olc, f);
                float h = oo * cp[e];
                out[t]           = h;
                out[Bl + t]      = cp[e];
                out[2 * Bl + t]  = ol1 * cp[e];
                out[3 * Bl + t]  = olc * cp[e];
                out[4 * Bl + t]  = 0.0f;
                out[5 * Bl + t]  = 0.0f;
                out[6 * Bl + t]  = oo;
                out[7 * Bl + t]  = ol1;
                out[8 * Bl + t]  = olc;
                out[9 * Bl + t]  = f;
                out[10 * Bl + 2 * t]     = h;
                out[10 * Bl + 2 * t + 1] = ostd;
                out[12 * Bl + t] = ostd;
            }
        }
    }
}

// ---------------- host launch ----------------

extern "C" void kernel_launch(void* const* d_in, const int* in_sizes, int n_in,
                              void* d_out, int out_size, void* d_ws, size_t ws_size,
                              hipStream_t stream) {
    const float* x        = (const float*)d_in[0];
    // d_in[1] = epoch (unused)
    const int*   time_lag = (const int*)d_in[2];
    const float* y_obs    = (const float*)d_in[3];
    const float* c_mean   = (const float*)d_in[4];
    const float* c_std    = (const float*)d_in[5];
    const float* w_yom    = (const float*)d_in[6];
    const float* w_ylm    = (const float*)d_in[7];
    const float* w_yfm    = (const float*)d_in[8];
    const float* b0       = (const float*)d_in[9];
    const float* wb1      = (const float*)d_in[10];
    float* out = (float*)d_out;

    const int B = in_sizes[0] / 2;   // SEQ=1, IN=2

    double* part = (double*)d_ws;

    partial_std_kernel<<<NPART, 256, 0, stream>>>(y_obs, part);

    const int blocks = (B + RPB - 1) / RPB;          // 489 for B = 2e6
    scan_kernel<<<blocks, BLK, 0, stream>>>(x, time_lag, c_mean, c_std,
                                            w_yom, w_ylm, w_yfm, b0, wb1,
                                            part, out, B);
}

// Round 8
// 151.686 us; speedup vs baseline: 1.7021x; 1.0178x over previous
//
#include <hip/hip_runtime.h>
#include <math.h>

#define SPIN 365
#define TRAIN 1000000
#define WARM 64
#define TPW 512                     // output rows per wave (tile)
#define BLK 512                     // threads per block (8 waves)
#define WPB (BLK / 64)              // waves per block
#define XROWS (TPW + WARM)          // staged rows per wave = 576
#define XSEG (2 * XROWS + XROWS / 16)   // 1188 floats per wave
#define CSEG (64 * 9)               // c_pre floats per wave (stride 9)
#define NPART 256

// ---------------- obsstd partial reduction (double precision) ----------------

__global__ void partial_std_kernel(const float* __restrict__ y, double* __restrict__ part) {
    int tid = blockIdx.x * blockDim.x + threadIdx.x;
    int stride = gridDim.x * blockDim.x;
    double s = 0.0, s2 = 0.0;
    for (int i = SPIN + tid; i < TRAIN; i += stride) {
        double v = (double)y[i];
        s += v;
        s2 += v * v;
    }
    for (int off = 32; off > 0; off >>= 1) {
        s  += __shfl_down(s,  off, 64);
        s2 += __shfl_down(s2, off, 64);
    }
    __shared__ double ls[4], ls2[4];
    int lane = threadIdx.x & 63, w = threadIdx.x >> 6;
    if (lane == 0) { ls[w] = s; ls2[w] = s2; }
    __syncthreads();
    if (threadIdx.x == 0) {
        double ts = 0.0, ts2 = 0.0;
        int nw = blockDim.x >> 6;
        for (int i = 0; i < nw; ++i) { ts += ls[i]; ts2 += ls2[i]; }
        part[2 * blockIdx.x]     = ts;
        part[2 * blockIdx.x + 1] = ts2;
    }
}

// ---------------- main chunk-parallel scan (wave-autonomous, barrier-free) ----

struct Par { float oo1, ol1, ez1, ez0; };

// State update only: olc*c = c>0 ? min(ol1*c, u2) : ol1*c (identical, rcp-free).
__device__ __forceinline__ void step_state(float& c, float u1, float u2, const Par p) {
    float e   = __builtin_amdgcn_exp2f(fmaf(c, p.ez1, p.ez0));  // exp(-z)
    float sg  = __builtin_amdgcn_rcpf(1.0f + e);                // sigmoid(z)
    float ooc = p.oo1 * sg * c;
    float lc  = p.ol1 * c;
    float mlc = (c > 0.0f) ? fminf(lc, u2) : lc;
    c = c - ooc - mlc + u1;
}

// Full gates for Phase B (reference formulation per-output).
__device__ __forceinline__ void gates(float c, float u2, const Par p,
                                      float& oo, float& olc, float& f) {
    float e  = __builtin_amdgcn_exp2f(fmaf(c, p.ez1, p.ez0));
    float sg = __builtin_amdgcn_rcpf(1.0f + e);
    oo = p.oo1 * sg;
    float rc = __builtin_amdgcn_rcpf(c);
    float q  = u2 * rc;
    float olc_pos = fminf(p.ol1, q);
    olc = (c > 0.0f) ? olc_pos : p.ol1;
    f = 1.0f - oo - olc;
}

// Wave-local LDS x layout: interleaved (u1,u2), +1 dword pad per 16 rows.
__device__ __forceinline__ void ldu(const float* __restrict__ up, int off,
                                    float& a, float& b) {
    int idx = 2 * off + (off >> 4);
    a = up[idx];
    b = up[idx + 1];
}

__global__ __launch_bounds__(BLK, 4)
void scan_kernel(const float* __restrict__ x,
                 const int*  __restrict__ time_lag_p,
                 const float* __restrict__ cm, const float* __restrict__ cs,
                 const float* __restrict__ wro, const float* __restrict__ wrl,
                 const float* __restrict__ wrf, const float* __restrict__ b0p,
                 const float* __restrict__ wb1p,
                 const double* __restrict__ part,
                 float* __restrict__ out, int Btot) {
    __shared__ float s_x[WPB * XSEG];   // 38016 B
    __shared__ float s_c[WPB * CSEG];   // 18432 B
    // NO __syncthreads anywhere: all LDS traffic is wave-local (DS ops are
    // FIFO per wave, so a wave's ds_reads see its earlier ds_writes).

    const long long Bl = (long long)Btot;
    const int tl   = time_lag_p[0];
    const int tid  = threadIdx.x;
    const int wid  = tid >> 6;
    const int lane = tid & 63;

    // rows b < time_lag: all outputs zero (no-op when tl == 0)
    if (tl > 0) {
        long long gstride = (long long)gridDim.x * BLK;
        for (long long b = (long long)blockIdx.x * BLK + tid; b < tl; b += gstride) {
            for (int s = 0; s < 10; ++s) out[(long long)s * Bl + b] = 0.0f;
            out[10 * Bl + 2 * b]     = 0.0f;
            out[10 * Bl + 2 * b + 1] = 0.0f;
            out[12 * Bl + b] = 0.0f;
        }
    }

    const long long gw = (long long)blockIdx.x * WPB + wid;   // global wave id
    const long long r0 = (long long)tl + gw * TPW;            // wave's first output row
    if (r0 >= Bl) return;                                     // whole wave exits (no barriers)

    // uniform scalars
    const float wo = wro[0], wl = wrl[0], wf = wrf[0];
    const float b0 = b0p[0], wb1 = wb1p[0], mo = cm[0], so = cs[0];
    const float eo = __expf(wo), el = __expf(wl), ef = __expf(wf);
    const float denom = eo + el + ef;
    const float kz1 = wb1 / so;
    const float kz0 = b0 - mo * kz1;
    const float LOG2E = 1.4426950408889634f;
    Par par;
    par.oo1 = eo / denom;
    par.ol1 = el / denom;
    par.ez1 = -kz1 * LOG2E;
    par.ez0 = -kz0 * LOG2E;
    const float ol1 = par.ol1;

    // per-wave obsstd final reduction (4 KB, L2-hot; overlaps other waves' work)
    double s = 0.0, s2 = 0.0;
    for (int i = lane; i < NPART; i += 64) {
        s  += part[2 * i];
        s2 += part[2 * i + 1];
    }
    for (int off = 32; off > 0; off >>= 1) {
        s  += __shfl_down(s,  off, 64);
        s2 += __shfl_down(s2, off, 64);
    }
    s  = __shfl(s, 0, 64);
    s2 = __shfl(s2, 0, 64);
    const double nn = (double)(TRAIN - SPIN);
    const float ostd = (float)sqrt((s2 - s * s / nn) / (nn - 1.0));

    const long long base    = r0 - WARM;        // first staged row (may be < tl)
    const long long lastrow = Bl - 1;
    float* sx = s_x + wid * XSEG;
    float* sc = s_c + wid * CSEG;

    // ---- stage this wave's x window [r0-WARM, r0+TPW) into its LDS segment ----
    #pragma unroll
    for (int k = 0; k < XROWS / 64; ++k) {      // 9 coalesced float2 loads
        int off = k * 64 + lane;
        long long row = base + off;
        row = row < 0 ? 0 : (row > lastrow ? lastrow : row);
        float2 v = *(const float2*)(x + 2 * row);
        int idx = 2 * off + (off >> 4);
        sx[idx]     = v.x;
        sx[idx + 1] = v.y;
    }

    // ---- Phase A: per-thread recurrence (8 rows), c_pre -> wave LDS ----
    {
        const long long rt = r0 + (long long)lane * 8;
        if (rt < Bl) {
            long long wstart = rt - WARM;
            if (wstart < tl) wstart = tl;
            const int nwarm = (int)(rt - wstart);
            long long lenl = Bl - rt;
            const int len = lenl > 8 ? 8 : (int)lenl;
            const int off0 = (int)(wstart - base);

            float c = 0.0f;                     // exact when clamped to tl
            float aA[8], bA[8], aB[8], bB[8];

            if (nwarm == WARM) {                // common path
                #pragma unroll
                for (int q = 0; q < 8; ++q) ldu(sx, off0 + q, aA[q], bA[q]);
                #pragma unroll
                for (int g = 0; g < 4; ++g) {   // 64 warm steps, ping-pong
                    #pragma unroll
                    for (int q = 0; q < 8; ++q) ldu(sx, off0 + (2 * g + 1) * 8 + q, aB[q], bB[q]);
                    #pragma unroll
                    for (int q = 0; q < 8; ++q) step_state(c, aA[q], bA[q], par);
                    #pragma unroll
                    for (int q = 0; q < 8; ++q) ldu(sx, off0 + (2 * g + 2) * 8 + q, aA[q], bA[q]);
                    #pragma unroll
                    for (int q = 0; q < 8; ++q) step_state(c, aB[q], bB[q], par);
                }
                // aA/bA now hold the 8 output rows
            } else {                            // first 8 lanes of tile 0 only
                for (int t = 0; t < nwarm; ++t) {
                    float ua, ub;
                    ldu(sx, off0 + t, ua, ub);
                    step_state(c, ua, ub, par);
                }
                #pragma unroll
                for (int q = 0; q < 8; ++q) ldu(sx, off0 + nwarm + q, aA[q], bA[q]);
            }

            float* my = sc + lane * 9;
            #pragma unroll
            for (int j = 0; j < 8; ++j) {
                if (j < len) my[j] = c;         // pre-update state
                step_state(c, aA[j], bA[j], par);
            }
        }
    }

    // ---- Phase B: re-derive gates from wave-local c_pre, coalesced stores ----
    const bool aligned = ((tl & 3) == 0);
    const float4 z4  = make_float4(0.0f, 0.0f, 0.0f, 0.0f);
    const float4 ol4 = make_float4(ol1, ol1, ol1, ol1);
    const float4 os4 = make_float4(ostd, ostd, ostd, ostd);

    #pragma unroll
    for (int h = 0; h < 2; ++h) {
        const int rl = h * 256 + lane * 4;      // local row (multiple of 4)
        const long long r = r0 + rl;
        if (r >= Bl) continue;

        const int sidx = rl >> 3;               // producer lane (same wave)
        const int j0   = (lane & 1) * 4;        // element offset within producer
        float cp[4], u2v[4];
        #pragma unroll
        for (int e = 0; e < 4; ++e) {
            cp[e] = sc[sidx * 9 + j0 + e];
            float ua, ub;
            ldu(sx, WARM + rl + e, ua, ub);
            u2v[e] = ub;
        }

        if (aligned && (r + 3 < Bl)) {
            float h4[4], lo[4], lc[4], go[4], gc[4], gf[4];
            #pragma unroll
            for (int e = 0; e < 4; ++e) {
                float oo, olc, f;
                gates(cp[e], u2v[e], par, oo, olc, f);
                h4[e] = oo * cp[e];
                lo[e] = ol1 * cp[e];
                lc[e] = olc * cp[e];
                go[e] = oo;
                gc[e] = olc;
                gf[e] = f;
            }
            *(float4*)(out + r)          = make_float4(h4[0], h4[1], h4[2], h4[3]);
            *(float4*)(out + Bl + r)     = make_float4(cp[0], cp[1], cp[2], cp[3]);
            *(float4*)(out + 2 * Bl + r) = make_float4(lo[0], lo[1], lo[2], lo[3]);
            *(float4*)(out + 3 * Bl + r) = make_float4(lc[0], lc[1], lc[2], lc[3]);
            *(float4*)(out + 4 * Bl + r) = z4;
            *(float4*)(out + 5 * Bl + r) = z4;
            *(float4*)(out + 6 * Bl + r) = make_float4(go[0], go[1], go[2], go[3]);
            *(float4*)(out + 7 * Bl + r) = ol4;
            *(float4*)(out + 8 * Bl + r) = make_float4(gc[0], gc[1], gc[2], gc[3]);
            *(float4*)(out + 9 * Bl + r) = make_float4(gf[0], gf[1], gf[2], gf[3]);
            *(float4*)(out + 10 * Bl + 2 * r)     = make_float4(h4[0], ostd, h4[1], ostd);
            *(float4*)(out + 10 * Bl + 2 * r + 4) = make_float4(h4[2], ostd, h4[3], ostd);
            *(float4*)(out + 12 * Bl + r) = os4;
        } else {
            #pragma unroll
            for (int e = 0; e < 4; ++e) {
                long long t = r + e;
                if (t >= Bl) break;
                float oo, olc, f;
                gates(cp[e], u2v[e], par, oo, olc, f);
                float hh = oo * cp[e];
                out[t]           = hh;
                out[Bl + t]      = cp[e];
                out[2 * Bl + t]  = ol1 * cp[e];
                out[3 * Bl + t]  = olc * cp[e];
                out[4 * Bl + t]  = 0.0f;
                out[5 * Bl + t]  = 0.0f;
                out[6 * Bl + t]  = oo;
                out[7 * Bl + t]  = ol1;
                out[8 * Bl + t]  = olc;
                out[9 * Bl + t]  = f;
                out[10 * Bl + 2 * t]     = hh;
                out[10 * Bl + 2 * t + 1] = ostd;
                out[12 * Bl + t] = ostd;
            }
        }
    }
}

// ---------------- host launch ----------------

extern "C" void kernel_launch(void* const* d_in, const int* in_sizes, int n_in,
                              void* d_out, int out_size, void* d_ws, size_t ws_size,
                              hipStream_t stream) {
    const float* x        = (const float*)d_in[0];
    // d_in[1] = epoch (unused)
    const int*   time_lag = (const int*)d_in[2];
    const float* y_obs    = (const float*)d_in[3];
    const float* c_mean   = (const float*)d_in[4];
    const float* c_std    = (const float*)d_in[5];
    const float* w_yom    = (const float*)d_in[6];
    const float* w_ylm    = (const float*)d_in[7];
    const float* w_yfm    = (const float*)d_in[8];
    const float* b0       = (const float*)d_in[9];
    const float* wb1      = (const float*)d_in[10];
    float* out = (float*)d_out;

    const int B = in_sizes[0] / 2;   // SEQ=1, IN=2

    double* part = (double*)d_ws;

    partial_std_kernel<<<NPART, 256, 0, stream>>>(y_obs, part);

    // one 512-row tile per wave; worst case tl=0 -> ceil(B/512) tiles
    const long long ntiles = ((long long)B + TPW - 1) / TPW;
    const int blocks = (int)((ntiles + WPB - 1) / WPB);      // 489 for B = 2e6
    scan_kernel<<<blocks, BLK, 0, stream>>>(x, time_lag, c_mean, c_std,
                                            w_yom, w_ylm, w_yfm, b0, wb1,
                                            part, out, B);
}